// Round 5
// baseline (899.150 us; speedup 1.0000x reference)
//
#include <hip/hip_runtime.h>

// EdgeBlock: out = relu(concat(node[snd], node[rcv], edge) @ w1 + b1) @ w2 + b2
// E=800000, N=50000, D=128. fp32 in/out, fp16 MFMA.
// r5: both weights fragment-major in global (L2-hot, coalesced B-frag loads);
// LDS = per-wave 8KB A/h buffer only -> 32KB/block -> 5 blocks/CU = 20 waves/CU.

#define NE 800000
#define DD 128

typedef float f32x4v __attribute__((ext_vector_type(4)));
typedef float f32x16 __attribute__((ext_vector_type(16)));
typedef _Float16 f16x8 __attribute__((ext_vector_type(8)));
typedef _Float16 f16x4 __attribute__((ext_vector_type(4)));

__device__ __forceinline__ f16x4 cvt4(f32x4v v) {
    f16x4 r;
    r[0] = (_Float16)v[0]; r[1] = (_Float16)v[1];
    r[2] = (_Float16)v[2]; r[3] = (_Float16)v[3];
    return r;
}

// Fragment-major weights: wf[(kk2*128 + col)*8 + j] = w[(kk2*8 + j)*128 + col]
// w1f: kk2 = 0..47 (96KB fp16), w2f: kk2 = 0..15 (32KB fp16)
__global__ void prep_w(const float* __restrict__ w1, const float* __restrict__ w2,
                       _Float16* __restrict__ w1f, _Float16* __restrict__ w2f) {
    int i = blockIdx.x * 256 + threadIdx.x;   // 65536 total
    if (i < 48 * 128 * 8) {
        int kk2 = i >> 10;
        int col = (i >> 3) & 127;
        int j = i & 7;
        w1f[i] = (_Float16)w1[(size_t)(kk2 * 8 + j) * 128 + col];
    } else {
        int t = i - 48 * 128 * 8;
        int kk2 = t >> 10;
        int col = (t >> 3) & 127;
        int j = t & 7;
        w2f[t] = (_Float16)w2[(size_t)(kk2 * 8 + j) * 128 + col];
    }
}

__global__ __attribute__((amdgpu_flat_work_group_size(256, 256),
                          amdgpu_waves_per_eu(5, 5)))
void edge_mlp(
    const float* __restrict__ node_attr,
    const int* __restrict__ eidx,
    const float* __restrict__ edge_attr,
    const _Float16* __restrict__ w1f,   // fragment-major, 96KB (L2)
    const float* __restrict__ b1,
    const _Float16* __restrict__ w2f,   // fragment-major, 32KB (L1/L2)
    const float* __restrict__ b2,
    float* __restrict__ out) {
    __shared__ _Float16 abuf[4][4096];   // 4 waves x 8KB A/h buffer = 32KB

    const int tid = threadIdx.x;
    const int wid = tid >> 6;
    const int lane = tid & 63;
    const int r31 = lane & 31;
    const int g2 = lane >> 5;
    const int sub = g2;           // row selector within gathered pair
    const int c4 = r31;           // float4 index within row

    char* ab = (char*)abuf[wid];
    const int ebase = blockIdx.x * 128 + wid * 32;

    const int sidx = eidx[ebase + r31];
    const int ridx = eidx[NE + ebase + r31];

    float b1v[4], b2v[4];
    #pragma unroll
    for (int n = 0; n < 4; n++) { b1v[n] = b1[n * 32 + r31]; b2v[n] = b2[n * 32 + r31]; }

    // ---- issue ALL gathers up front (sv, rv, ev in flight together) ----
    f32x4v sv[16], rv[16], ev[16];
    #pragma unroll
    for (int i = 0; i < 16; i++) {
        int r = __shfl(sidx, 2 * i + sub);
        sv[i] = *(const f32x4v*)(node_attr + (size_t)r * DD + c4 * 4);
    }
    #pragma unroll
    for (int i = 0; i < 16; i++) {
        int r = __shfl(ridx, 2 * i + sub);
        rv[i] = *(const f32x4v*)(node_attr + (size_t)r * DD + c4 * 4);
    }
    #pragma unroll
    for (int i = 0; i < 16; i++) {
        const int row = 2 * i + sub;
        ev[i] = __builtin_nontemporal_load(
            (const f32x4v*)(edge_attr + (size_t)(ebase + row) * DD + c4 * 4));
    }

    const int xa = (r31 & 15) << 4;   // A-read swizzle

    f32x16 acc[4] = {};

    // ---- seg 0 (sender): LDS write then consume ----
    #pragma unroll
    for (int i = 0; i < 16; i++) {
        const int row = 2 * i + sub;
        *(f16x4*)(ab + row * 256 + ((c4 * 8) ^ ((row & 15) << 4))) = cvt4(sv[i]);
    }
    __builtin_amdgcn_wave_barrier();
    #pragma unroll
    for (int kk8 = 0; kk8 < 8; kk8++) {
        f16x8 a = *(const f16x8*)(ab + r31 * 256 + ((kk8 * 32 + g2 * 16) ^ xa));
        const int kk = 0 * 8 + kk8;
        #pragma unroll
        for (int n = 0; n < 4; n++) {
            f16x8 b = *(const f16x8*)(w1f + ((size_t)((kk * 2 + g2) * 128 + n * 32 + r31)) * 8);
            acc[n] = __builtin_amdgcn_mfma_f32_32x32x16_f16(a, b, acc[n], 0, 0, 0);
        }
    }

    // ---- seg 1 (receiver) ----
    #pragma unroll
    for (int i = 0; i < 16; i++) {
        const int row = 2 * i + sub;
        *(f16x4*)(ab + row * 256 + ((c4 * 8) ^ ((row & 15) << 4))) = cvt4(rv[i]);
    }
    __builtin_amdgcn_wave_barrier();
    #pragma unroll
    for (int kk8 = 0; kk8 < 8; kk8++) {
        f16x8 a = *(const f16x8*)(ab + r31 * 256 + ((kk8 * 32 + g2 * 16) ^ xa));
        const int kk = 1 * 8 + kk8;
        #pragma unroll
        for (int n = 0; n < 4; n++) {
            f16x8 b = *(const f16x8*)(w1f + ((size_t)((kk * 2 + g2) * 128 + n * 32 + r31)) * 8);
            acc[n] = __builtin_amdgcn_mfma_f32_32x32x16_f16(a, b, acc[n], 0, 0, 0);
        }
    }

    // ---- seg 2 (edge), with GEMM2 B half-0 prefetch ----
    #pragma unroll
    for (int i = 0; i < 16; i++) {
        const int row = 2 * i + sub;
        *(f16x4*)(ab + row * 256 + ((c4 * 8) ^ ((row & 15) << 4))) = cvt4(ev[i]);
    }
    f16x8 b2fa[4][4];
    #pragma unroll
    for (int kk = 0; kk < 4; kk++)
        #pragma unroll
        for (int n = 0; n < 4; n++)
            b2fa[kk][n] = *(const f16x8*)(w2f + ((size_t)((kk * 2 + g2) * 128 + n * 32 + r31)) * 8);
    __builtin_amdgcn_wave_barrier();
    #pragma unroll
    for (int kk8 = 0; kk8 < 8; kk8++) {
        f16x8 a = *(const f16x8*)(ab + r31 * 256 + ((kk8 * 32 + g2 * 16) ^ xa));
        const int kk = 2 * 8 + kk8;
        #pragma unroll
        for (int n = 0; n < 4; n++) {
            f16x8 b = *(const f16x8*)(w1f + ((size_t)((kk * 2 + g2) * 128 + n * 32 + r31)) * 8);
            acc[n] = __builtin_amdgcn_mfma_f32_32x32x16_f16(a, b, acc[n], 0, 0, 0);
        }
    }

    // ---- bias + relu, h -> same LDS buffer ----
    #pragma unroll
    for (int n = 0; n < 4; n++) {
        const int col = n * 32 + r31;
        #pragma unroll
        for (int reg = 0; reg < 16; reg++) {
            const int row = (reg & 3) + 8 * (reg >> 2) + 4 * g2;
            float v = fmaxf(acc[n][reg] + b1v[n], 0.0f);
            *(_Float16*)(ab + row * 256 + ((col * 2) ^ ((row & 15) << 4))) = (_Float16)v;
        }
    }
    __builtin_amdgcn_wave_barrier();

    // ---------------- GEMM2: [32x128] @ [128x128] ----------------
    f32x16 acc2[4] = {};
    #pragma unroll
    for (int kk = 0; kk < 4; kk++) {
        f16x8 a = *(const f16x8*)(ab + r31 * 256 + ((kk * 32 + g2 * 16) ^ xa));
        #pragma unroll
        for (int n = 0; n < 4; n++)
            acc2[n] = __builtin_amdgcn_mfma_f32_32x32x16_f16(a, b2fa[kk][n], acc2[n], 0, 0, 0);
    }
    f16x8 b2fb[4][4];
    #pragma unroll
    for (int kk = 0; kk < 4; kk++)
        #pragma unroll
        for (int n = 0; n < 4; n++)
            b2fb[kk][n] = *(const f16x8*)(w2f + ((size_t)(((kk + 4) * 2 + g2) * 128 + n * 32 + r31)) * 8);
    #pragma unroll
    for (int kk = 4; kk < 8; kk++) {
        f16x8 a = *(const f16x8*)(ab + r31 * 256 + ((kk * 32 + g2 * 16) ^ xa));
        #pragma unroll
        for (int n = 0; n < 4; n++)
            acc2[n] = __builtin_amdgcn_mfma_f32_32x32x16_f16(a, b2fb[kk - 4][n], acc2[n], 0, 0, 0);
    }

    // ---- bias + store fp32 (2x128B lines per instr, nontemporal) ----
    #pragma unroll
    for (int n = 0; n < 4; n++) {
        #pragma unroll
        for (int reg = 0; reg < 16; reg++) {
            const int row = (reg & 3) + 8 * (reg >> 2) + 4 * g2;
            __builtin_nontemporal_store(acc2[n][reg] + b2v[n],
                out + (size_t)(ebase + row) * DD + n * 32 + r31);
        }
    }
}

extern "C" void kernel_launch(void* const* d_in, const int* in_sizes, int n_in,
                              void* d_out, int out_size, void* d_ws, size_t ws_size,
                              hipStream_t stream) {
    const float* node_attr = (const float*)d_in[0];
    const int* eidx = (const int*)d_in[1];
    const float* edge_attr = (const float*)d_in[2];
    const float* w1 = (const float*)d_in[3];
    const float* b1 = (const float*)d_in[4];
    const float* w2 = (const float*)d_in[5];
    const float* b2 = (const float*)d_in[6];
    float* out = (float*)d_out;

    _Float16* w1f = (_Float16*)d_ws;            // 96KB fragment-major
    _Float16* w2f = w1f + 48 * 128 * 8;         // 32KB fragment-major

    prep_w<<<256, 256, 0, stream>>>(w1, w2, w1f, w2f);
    edge_mlp<<<6250, 256, 0, stream>>>(node_attr, eidx, edge_attr,
                                       w1f, b1, w2f, b2, out);
}

// Round 6
// 636.146 us; speedup vs baseline: 1.4134x; 1.4134x over previous
//
#include <hip/hip_runtime.h>

// EdgeBlock: out = relu(concat(node[snd], node[rcv], edge) @ w1 + b1) @ w2 + b2
// E=800000, N=50000, D=128. fp32 in/out, fp16 MFMA.
// r6 = r4's staged gather ordering (no spills, 92-reg live set)
//    + r5's fragment-major global weights (no 96KB LDS block)
//    + 32KB static LDS, waves_per_eu(4,4) -> target 16 waves/CU.

#define NE 800000
#define DD 128

typedef float f32x4v __attribute__((ext_vector_type(4)));
typedef float f32x16 __attribute__((ext_vector_type(16)));
typedef _Float16 f16x8 __attribute__((ext_vector_type(8)));
typedef _Float16 f16x4 __attribute__((ext_vector_type(4)));

__device__ __forceinline__ f16x4 cvt4(f32x4v v) {
    f16x4 r;
    r[0] = (_Float16)v[0]; r[1] = (_Float16)v[1];
    r[2] = (_Float16)v[2]; r[3] = (_Float16)v[3];
    return r;
}

// Fragment-major weights: wf[(kk2*128 + col)*8 + j] = w[(kk2*8 + j)*128 + col]
// w1f: kk2 = 0..47 (96KB fp16), w2f: kk2 = 0..15 (32KB fp16)
__global__ void prep_w(const float* __restrict__ w1, const float* __restrict__ w2,
                       _Float16* __restrict__ w1f, _Float16* __restrict__ w2f) {
    int i = blockIdx.x * 256 + threadIdx.x;   // 65536 total
    if (i < 48 * 128 * 8) {
        int kk2 = i >> 10;
        int col = (i >> 3) & 127;
        int j = i & 7;
        w1f[i] = (_Float16)w1[(size_t)(kk2 * 8 + j) * 128 + col];
    } else {
        int t = i - 48 * 128 * 8;
        int kk2 = t >> 10;
        int col = (t >> 3) & 127;
        int j = t & 7;
        w2f[t] = (_Float16)w2[(size_t)(kk2 * 8 + j) * 128 + col];
    }
}

__global__ __attribute__((amdgpu_flat_work_group_size(256, 256),
                          amdgpu_waves_per_eu(4, 4)))
void edge_mlp(
    const float* __restrict__ node_attr,
    const int* __restrict__ eidx,
    const float* __restrict__ edge_attr,
    const _Float16* __restrict__ w1f,   // fragment-major, 96KB (L2/L3)
    const float* __restrict__ b1,
    const _Float16* __restrict__ w2f,   // fragment-major, 32KB (L1/L2)
    const float* __restrict__ b2,
    float* __restrict__ out) {
    __shared__ _Float16 abuf[4][4096];   // 4 waves x 8KB A/h buffer = 32KB

    const int tid = threadIdx.x;
    const int wid = tid >> 6;
    const int lane = tid & 63;
    const int r31 = lane & 31;
    const int g2 = lane >> 5;
    const int sub = g2;           // row selector within gathered pair
    const int c4 = r31;           // float4 index within row

    char* ab = (char*)abuf[wid];
    const int ebase = blockIdx.x * 128 + wid * 32;

    const int sidx = eidx[ebase + r31];
    const int ridx = eidx[NE + ebase + r31];

    float b1v[4], b2v[4];
    #pragma unroll
    for (int n = 0; n < 4; n++) { b1v[n] = b1[n * 32 + r31]; b2v[n] = b2[n * 32 + r31]; }

    const int xa = (r31 & 15) << 4;   // A-read swizzle

    // ---- gather sender rows: 2 rows per instr, coalesced 128B segments ----
    f32x4v sv[16];
    #pragma unroll
    for (int i = 0; i < 16; i++) {
        int r = __shfl(sidx, 2 * i + sub);
        sv[i] = *(const f32x4v*)(node_attr + (size_t)r * DD + c4 * 4);
    }
    // write seg S to LDS (cvt f16, swizzled)
    #pragma unroll
    for (int i = 0; i < 16; i++) {
        const int row = 2 * i + sub;
        *(f16x4*)(ab + row * 256 + ((c4 * 8) ^ ((row & 15) << 4))) = cvt4(sv[i]);
    }

    // issue receiver gathers (fly during seg-S MFMAs)
    f32x4v rv[16];
    #pragma unroll
    for (int i = 0; i < 16; i++) {
        int r = __shfl(ridx, 2 * i + sub);
        rv[i] = *(const f32x4v*)(node_attr + (size_t)r * DD + c4 * 4);
    }

    f32x16 acc[4] = {};
    __builtin_amdgcn_wave_barrier();

    // ---- consume seg 0 (sender) ----
    #pragma unroll
    for (int kk8 = 0; kk8 < 8; kk8++) {
        f16x8 a = *(const f16x8*)(ab + r31 * 256 + ((kk8 * 32 + g2 * 16) ^ xa));
        const int kk = 0 * 8 + kk8;
        #pragma unroll
        for (int n = 0; n < 4; n++) {
            f16x8 b = *(const f16x8*)(w1f + ((size_t)((kk * 2 + g2) * 128 + n * 32 + r31)) * 8);
            acc[n] = __builtin_amdgcn_mfma_f32_32x32x16_f16(a, b, acc[n], 0, 0, 0);
        }
    }

    // write seg R, issue edge loads
    #pragma unroll
    for (int i = 0; i < 16; i++) {
        const int row = 2 * i + sub;
        *(f16x4*)(ab + row * 256 + ((c4 * 8) ^ ((row & 15) << 4))) = cvt4(rv[i]);
    }
    f32x4v ev[16];
    #pragma unroll
    for (int i = 0; i < 16; i++) {
        const int row = 2 * i + sub;
        ev[i] = __builtin_nontemporal_load(
            (const f32x4v*)(edge_attr + (size_t)(ebase + row) * DD + c4 * 4));
    }
    __builtin_amdgcn_wave_barrier();

    // ---- consume seg 1 (receiver) ----
    #pragma unroll
    for (int kk8 = 0; kk8 < 8; kk8++) {
        f16x8 a = *(const f16x8*)(ab + r31 * 256 + ((kk8 * 32 + g2 * 16) ^ xa));
        const int kk = 1 * 8 + kk8;
        #pragma unroll
        for (int n = 0; n < 4; n++) {
            f16x8 b = *(const f16x8*)(w1f + ((size_t)((kk * 2 + g2) * 128 + n * 32 + r31)) * 8);
            acc[n] = __builtin_amdgcn_mfma_f32_32x32x16_f16(a, b, acc[n], 0, 0, 0);
        }
    }

    // write seg E; prefetch GEMM2 B half-0
    #pragma unroll
    for (int i = 0; i < 16; i++) {
        const int row = 2 * i + sub;
        *(f16x4*)(ab + row * 256 + ((c4 * 8) ^ ((row & 15) << 4))) = cvt4(ev[i]);
    }
    f16x8 b2fa[4][4];
    #pragma unroll
    for (int kk = 0; kk < 4; kk++)
        #pragma unroll
        for (int n = 0; n < 4; n++)
            b2fa[kk][n] = *(const f16x8*)(w2f + ((size_t)((kk * 2 + g2) * 128 + n * 32 + r31)) * 8);
    __builtin_amdgcn_wave_barrier();

    // ---- consume seg 2 (edge) ----
    #pragma unroll
    for (int kk8 = 0; kk8 < 8; kk8++) {
        f16x8 a = *(const f16x8*)(ab + r31 * 256 + ((kk8 * 32 + g2 * 16) ^ xa));
        const int kk = 2 * 8 + kk8;
        #pragma unroll
        for (int n = 0; n < 4; n++) {
            f16x8 b = *(const f16x8*)(w1f + ((size_t)((kk * 2 + g2) * 128 + n * 32 + r31)) * 8);
            acc[n] = __builtin_amdgcn_mfma_f32_32x32x16_f16(a, b, acc[n], 0, 0, 0);
        }
    }

    // ---- bias + relu, h -> same LDS buffer (seg data dead) ----
    #pragma unroll
    for (int n = 0; n < 4; n++) {
        const int col = n * 32 + r31;
        #pragma unroll
        for (int reg = 0; reg < 16; reg++) {
            const int row = (reg & 3) + 8 * (reg >> 2) + 4 * g2;
            float v = fmaxf(acc[n][reg] + b1v[n], 0.0f);
            *(_Float16*)(ab + row * 256 + ((col * 2) ^ ((row & 15) << 4))) = (_Float16)v;
        }
    }
    __builtin_amdgcn_wave_barrier();

    // ---------------- GEMM2: [32x128] @ [128x128] ----------------
    f32x16 acc2[4] = {};
    #pragma unroll
    for (int kk = 0; kk < 4; kk++) {
        f16x8 a = *(const f16x8*)(ab + r31 * 256 + ((kk * 32 + g2 * 16) ^ xa));
        #pragma unroll
        for (int n = 0; n < 4; n++)
            acc2[n] = __builtin_amdgcn_mfma_f32_32x32x16_f16(a, b2fa[kk][n], acc2[n], 0, 0, 0);
    }
    f16x8 b2fb[4][4];
    #pragma unroll
    for (int kk = 0; kk < 4; kk++)
        #pragma unroll
        for (int n = 0; n < 4; n++)
            b2fb[kk][n] = *(const f16x8*)(w2f + ((size_t)(((kk + 4) * 2 + g2) * 128 + n * 32 + r31)) * 8);
    #pragma unroll
    for (int kk = 4; kk < 8; kk++) {
        f16x8 a = *(const f16x8*)(ab + r31 * 256 + ((kk * 32 + g2 * 16) ^ xa));
        #pragma unroll
        for (int n = 0; n < 4; n++)
            acc2[n] = __builtin_amdgcn_mfma_f32_32x32x16_f16(a, b2fb[kk - 4][n], acc2[n], 0, 0, 0);
    }

    // ---- bias + store fp32 (coalesced 128B lines, nontemporal) ----
    #pragma unroll
    for (int n = 0; n < 4; n++) {
        #pragma unroll
        for (int reg = 0; reg < 16; reg++) {
            const int row = (reg & 3) + 8 * (reg >> 2) + 4 * g2;
            __builtin_nontemporal_store(acc2[n][reg] + b2v[n],
                out + (size_t)(ebase + row) * DD + n * 32 + r31);
        }
    }
}

extern "C" void kernel_launch(void* const* d_in, const int* in_sizes, int n_in,
                              void* d_out, int out_size, void* d_ws, size_t ws_size,
                              hipStream_t stream) {
    const float* node_attr = (const float*)d_in[0];
    const int* eidx = (const int*)d_in[1];
    const float* edge_attr = (const float*)d_in[2];
    const float* w1 = (const float*)d_in[3];
    const float* b1 = (const float*)d_in[4];
    const float* w2 = (const float*)d_in[5];
    const float* b2 = (const float*)d_in[6];
    float* out = (float*)d_out;

    _Float16* w1f = (_Float16*)d_ws;            // 96KB fragment-major
    _Float16* w2f = w1f + 48 * 128 * 8;         // 32KB fragment-major

    prep_w<<<256, 256, 0, stream>>>(w1, w2, w1f, w2f);
    edge_mlp<<<6250, 256, 0, stream>>>(node_attr, eidx, edge_attr,
                                       w1f, b1, w2f, b2, out);
}